// Round 6
// baseline (116.156 us; speedup 1.0000x reference)
//
#include <hip/hip_runtime.h>

// ToeplitzMemoryProjection (HiPPO LagT, alpha=0.5 bilinear).
//
// Math: with c = 1 + 0.25*dt, g = (1-0.25*dt)/c, beta = dt*u/c, the step
// operator is (g*I - S)(I - g*S)^{-1} (S = down-shift) and the input term is
// beta*(I - g*S)^{-1} e0. Multiplying the scan x_l = A_l x_{l-1} + B_l by
// (I - g_l S) (exact in the truncated lower-tri Toeplitz algebra) gives the
// O(N)-per-step recurrence
//
//   x_l[i] = g_l*(x_l[i-1] + x_{l-1}[i]) - x_{l-1}[i-1] + beta_l*[i==0]
//
// Lane-skewed wavefront: 1 block/channel (256 ch), 256 threads (col = tid),
// thread i handles row l at tick T = l + wave*SKEW + lane.
//
// ROUND-6: the kernel was LDS-op-count bound (~512 b32 DS ops/CU/chunk at
// ~5 cy each) with stores bursting only at chunk end. Changes:
//  - g values ride a DPP chain (lane i's g at tick T == lane i-1's at T-1):
//    g_cur = lane0 ? inject[s] : dpp_shr1(g_cur). Replaces 48 per-lane b32
//    reads with 12 broadcast ds_read_b128 (16 B/op) per chunk.
//  - KCH=48, SKEW=112, barriers 43 -> 30. Invariants: handoff staleness
//    SKEW-63 = 49 > KCH-1 ✓; handoff-read vs concurrent-write slot distance
//    (T0+47)-(T0-49) = 96 < 128 ✓; flush window (with 1-group lag) =
//    (T0+47)-(T0-75) = 122 < 128 ✓.
//  - flush split into 4 sub-batches of 12, software-pipelined: sub-batch k's
//    ring reads are issued BEFORE tick group k (its rows completed in group
//    k-1: lane63 tick of row nf+12k+j is T0-12+12k+j < T0+12k), stores after
//    the group. Read latency hides under ticks; stores spread evenly.
//  - barriers stay LDS-only (no vmcnt drain).

namespace {

constexpr int LLEN  = 1024;              // L
constexpr int NCHAN = 256;               // B*M
constexpr int NWAVE = 4;                 // waves per block (N = 256 cols)
constexpr int KCH   = 48;                // ticks per chunk (barrier period)
constexpr int SUB   = 12;                // ticks per flush sub-batch
constexpr int NSUB  = KCH / SUB;         // 4
constexpr int SKEW  = 64 + KCH;          // 112; staleness SKEW-63 = 49 > KCH-1
constexpr int RINGT = 128;               // tick-indexed ring slots (pow2)
constexpr int NCHUNK = 30;               // covers ticks [0,1440) >= 1423
constexpr int FLAG  = KCH + (64 - KCH + SUB) - 1;  // 75: fast nf = base_l-FLAG

constexpr int G_OFF = 0;
constexpr int B_OFF = LLEN;
constexpr int R_OFF = 2 * LLEN;
constexpr int LDS_FLOATS = R_OFF + NWAVE * RINGT * 64;
constexpr size_t LDS_BYTES = (size_t)LDS_FLOATS * sizeof(float);  // 139264 B

using f32x4 = __attribute__((ext_vector_type(4))) float;

__device__ __forceinline__ float dpp_wave_shr1(float v) {
    // v_mov_b32_dpp wave_shr:1 — lane i gets lane i-1's value, lane 0 gets 0.
    return __int_as_float(__builtin_amdgcn_update_dpp(
        0, __float_as_int(v), 0x138 /*WAVE_SHR1*/, 0xF, 0xF, false));
}

__device__ __forceinline__ unsigned lds_a(const void* p) {
    return (unsigned)(unsigned long long)p;
}
__device__ __forceinline__ void ds_read_b32_addr(float& d, unsigned a) {
    asm volatile("ds_read_b32 %0, %1" : "=v"(d) : "v"(a));
}
__device__ __forceinline__ void ds_read_b128_off(f32x4& d, unsigned a, int off) {
    asm volatile("ds_read_b128 %0, %1 offset:%2" : "=v"(d) : "v"(a), "i"(off));
}
__device__ __forceinline__ void wait_lgkm0_fence() {
    asm volatile("s_waitcnt lgkmcnt(0)" ::: "memory");
    __builtin_amdgcn_sched_barrier(0);
}
__device__ __forceinline__ void compiler_mem_fence() {
    asm volatile("" ::: "memory");
}
__device__ __forceinline__ void lds_barrier() {
    __builtin_amdgcn_sched_barrier(0);
    asm volatile("s_waitcnt lgkmcnt(0)" ::: "memory");
    __builtin_amdgcn_s_barrier();
    __builtin_amdgcn_sched_barrier(0);
}

// One KCH-tick chunk. Injection source gj = g[base_l + s] (per-wave chain
// head). lane0 extra source hbv: W0 -> beta b_arr[T0+s]; else left wave's
// ring column 63 at tick T0+s-(SKEW-63).
template <bool W0, bool MASKED, bool FLUSH>
__device__ __forceinline__ void do_chunk(
    const int T0, const int base_l, const int wskew,
    const int lane, const bool lane0,
    const unsigned g_base, const unsigned hb_base, const unsigned my_base,
    float* __restrict__ my_ring,
    float& g_cur, float& prev_own, float& prev_left,
    const int nf, float* __restrict__ ocol)
{
    float gj[KCH], hbv[KCH];
    compiler_mem_fence();
    // ---- gather cluster: 12 b128 broadcasts (fast) / 48 clamped b32 ----
    if (!MASKED) {
        const unsigned gb = g_base + 4u * (unsigned)base_l;   // 64B-aligned
        #pragma unroll
        for (int q = 0; q < KCH / 4; ++q) {
            f32x4 t; ds_read_b128_off(t, gb, 16 * q);
            gj[4*q+0] = t[0]; gj[4*q+1] = t[1];
            gj[4*q+2] = t[2]; gj[4*q+3] = t[3];
        }
    } else {
        #pragma unroll
        for (int s = 0; s < KCH; ++s) {
            const int li = min(max(base_l + s, 0), LLEN - 1);
            ds_read_b32_addr(gj[s], g_base + 4u * (unsigned)li);
        }
    }
    if (W0) {
        if (!MASKED) {
            const unsigned bb = hb_base + 4u * (unsigned)T0;  // 192B-aligned
            #pragma unroll
            for (int q = 0; q < KCH / 4; ++q) {
                f32x4 t; ds_read_b128_off(t, bb, 16 * q);
                hbv[4*q+0] = t[0]; hbv[4*q+1] = t[1];
                hbv[4*q+2] = t[2]; hbv[4*q+3] = t[3];
            }
        } else {
            #pragma unroll
            for (int s = 0; s < KCH; ++s) {
                const int ti = min(T0 + s, LLEN - 1);
                ds_read_b32_addr(hbv[s], hb_base + 4u * (unsigned)ti);
            }
        }
    } else {
        #pragma unroll
        for (int s = 0; s < KCH; ++s) {
            const unsigned slot =
                (unsigned)(T0 + s - (SKEW - 63)) & (RINGT - 1);
            ds_read_b32_addr(hbv[s], hb_base + (slot << 8) + 63u * 4u);
        }
    }
    wait_lgkm0_fence();

    #pragma unroll
    for (int k = 0; k < NSUB; ++k) {
        float tmp[SUB];
        if (FLUSH) {
            // rows nf+SUB*k .. +SUB-1 completed in group k-1 (lane63 tick
            // T0-12+12k+j < T0+12k): safe to read before this group's ticks.
            compiler_mem_fence();
            const int A = nf + SUB * k + wskew + lane;
            #pragma unroll
            for (int q = 0; q < SUB; ++q) {
                const unsigned slot = (unsigned)(A + q) & (RINGT - 1);
                ds_read_b32_addr(tmp[q],
                                 my_base + (slot << 8) + ((unsigned)lane << 2));
            }
        }
        // ---- SUB ticks: dpp chains (x and g), fire-and-forget ring write --
        #pragma unroll
        for (int s = 0; s < SUB; ++s) {
            const int sg = SUB * k + s;
            const float ginj = dpp_wave_shr1(g_cur);
            g_cur = lane0 ? gj[sg] : ginj;          // g[l] for this lane/tick
            float cl = dpp_wave_shr1(prev_own);     // x_l[i-1]
            const float sel = lane0 ? hbv[sg] : 0.0f;
            if (!W0) cl += sel;                     // lane0: left-wave handoff
            const float ct = (W0 ? sel : 0.0f) - prev_left;
            const float x = fmaf(g_cur, cl, fmaf(g_cur, prev_own, ct));
            my_ring[(((unsigned)(T0 + sg) & (RINGT - 1)) << 6) + lane] = x;
            if (MASKED) {
                const int l = base_l + sg - lane;
                const bool act = (l >= 0) & (l < LLEN);
                prev_left = act ? cl : prev_left;
                prev_own  = act ? x  : prev_own;
            } else {
                prev_left = cl;
                prev_own  = x;
            }
        }
        if (FLUSH) {
            wait_lgkm0_fence();   // drains flush reads (+ this group's writes)
            float* p = ocol + (size_t)(nf + SUB * k) * (NCHAN * 256);
            #pragma unroll
            for (int q = 0; q < SUB; ++q) {
                __builtin_nontemporal_store(tmp[q], p);
                p += NCHAN * 256;
            }
        }
    }
}

__global__ __launch_bounds__(256, 1)
void toeplitz_scan(const float* __restrict__ vin,   // inputs (L, 256)
                   const float* __restrict__ dtin,  // dt     (L, 256)
                   float* __restrict__ out)         // (L, 256, 256)
{
    extern __shared__ float lds[];
    float* g_arr = lds + G_OFF;   // [LLEN]
    float* b_arr = lds + B_OFF;   // [LLEN]
    float* ring  = lds + R_OFF;   // [NWAVE][RINGT][64], tick-indexed slots

    const int ch   = blockIdx.x;
    const int tid  = threadIdx.x;
    const int wave = tid >> 6;
    const int lane = tid & 63;

    // ---- precompute g[l], beta[l] for this channel ----
    #pragma unroll
    for (int k = 0; k < LLEN / 256; ++k) {
        const int l = tid + k * 256;
        const float d = dtin[l * NCHAN + ch];
        const float u = vin[l * NCHAN + ch];
        const float inv_c = 1.0f / (1.0f + 0.25f * d);
        g_arr[l] = (1.0f - 0.25f * d) * inv_c;
        b_arr[l] = d * u * inv_c;
    }
    __syncthreads();

    float* my_ring = ring + wave * (RINGT * 64);
    const unsigned g_base  = lds_a(g_arr);
    const unsigned b_base  = lds_a(b_arr);
    const unsigned my_base = lds_a(my_ring);
    const unsigned lf_base = lds_a(ring + (wave - 1) * (RINGT * 64)); // wave>0

    const int wskew  = wave * SKEW;
    const bool w0    = (wave == 0);
    const bool lane0 = (lane == 0);

    float g_cur = 0.0f, prev_own = 0.0f, prev_left = 0.0f;
    int nf = 0;                                   // next row to flush
    float* ocol = out + (ch * 256 + wave * 64 + lane);

    for (int c = 0; c < NCHUNK; ++c) {
        const int T0 = c * KCH;
        const int base_l = T0 - wskew;            // lane0's row at s=0
        const bool any_act = (base_l >= -(KCH - 1)) && (base_l <= LLEN - 1 + 63);

        if (any_act) {
            const unsigned hb = w0 ? b_base : lf_base;
            const bool fast = (base_l >= FLAG) && (base_l <= LLEN - KCH);
            if (fast) {                           // implies fully active
                if (w0)
                    do_chunk<true, false, true>(T0, base_l, wskew, lane, lane0,
                        g_base, hb, my_base, my_ring, g_cur, prev_own, prev_left,
                        nf, ocol);
                else
                    do_chunk<false, false, true>(T0, base_l, wskew, lane, lane0,
                        g_base, hb, my_base, my_ring, g_cur, prev_own, prev_left,
                        nf, ocol);
                nf += KCH;
            } else {
                const bool all_act = (base_l >= 63) && (base_l <= LLEN - KCH);
                if (w0) {
                    if (all_act)
                        do_chunk<true, false, false>(T0, base_l, wskew, lane,
                            lane0, g_base, hb, my_base, my_ring, g_cur,
                            prev_own, prev_left, nf, ocol);
                    else
                        do_chunk<true, true, false>(T0, base_l, wskew, lane,
                            lane0, g_base, hb, my_base, my_ring, g_cur,
                            prev_own, prev_left, nf, ocol);
                } else {
                    if (all_act)
                        do_chunk<false, false, false>(T0, base_l, wskew, lane,
                            lane0, g_base, hb, my_base, my_ring, g_cur,
                            prev_own, prev_left, nf, ocol);
                    else
                        do_chunk<false, true, false>(T0, base_l, wskew, lane,
                            lane0, g_base, hb, my_base, my_ring, g_cur,
                            prev_own, prev_left, nf, ocol);
                }
                // lagged tail flush (ramp/edge chunks): rows .. base_l-28
                compiler_mem_fence();
                const int hi = min(base_l - (64 - KCH) - SUB, LLEN - 1);
                for (; nf <= hi; ++nf) {
                    const int slot = (nf + wskew + lane) & (RINGT - 1);
                    __builtin_nontemporal_store(
                        my_ring[(slot << 6) + lane],
                        ocol + (size_t)nf * (NCHAN * 256));
                }
            }
        }
        lds_barrier();
    }

    // safety drain (ring values persist: no further writes after last chunk)
    compiler_mem_fence();
    for (; nf < LLEN; ++nf) {
        const int slot = (nf + wskew + lane) & (RINGT - 1);
        __builtin_nontemporal_store(my_ring[(slot << 6) + lane],
                                    ocol + (size_t)nf * (NCHAN * 256));
    }
}

} // namespace

extern "C" void kernel_launch(void* const* d_in, const int* in_sizes, int n_in,
                              void* d_out, int out_size, void* d_ws, size_t ws_size,
                              hipStream_t stream) {
    (void)in_sizes; (void)n_in; (void)d_ws; (void)ws_size; (void)out_size;
    const float* vin  = (const float*)d_in[0];   // "inputs"
    const float* dtin = (const float*)d_in[1];   // "dt"
    float* out = (float*)d_out;

    (void)hipFuncSetAttribute(reinterpret_cast<const void*>(toeplitz_scan),
                              hipFuncAttributeMaxDynamicSharedMemorySize,
                              (int)LDS_BYTES);

    toeplitz_scan<<<NCHAN, 256, LDS_BYTES, stream>>>(vin, dtin, out);
}

// Round 8
// 110.722 us; speedup vs baseline: 1.0491x; 1.0491x over previous
//
#include <hip/hip_runtime.h>

// ToeplitzMemoryProjection (HiPPO LagT, alpha=0.5 bilinear).
//
// Recurrence (exact in the truncated lower-tri Toeplitz algebra, verified
// rounds 1-6): with c = 1+0.25dt, g = (1-0.25dt)/c, beta = dt*u/c,
//   x_l[i] = g_l*(x_l[i-1] + x_{l-1}[i]) - x_{l-1}[i-1] + beta_l*[i==0]
//
// ROUND-8 = ROUND-7 with the compile fix: __builtin_nontemporal_store needs a
// clang ext_vector_type pointer, not HIP's float4 class type.
//
// TRANSPOSED decomposition (row-per-lane). Lane r owns row l of a 64-row
// tile and marches along columns; tick tau computes col c = tau - r.
//  - g, beta are PER-LANE CONSTANTS (no per-tick loads at all)
//  - up-neighbor row values arrive via ONE dpp wave_shr:1 per tick
//  - 16 tiles per channel chained via bnd[16][256] (tile k's lane63 row ->
//    tile k+1's lane0), scheduled at phase 3k + chunk (C=32 ticks/chunk,
//    55 phases); producer is always >= 1 barrier-phase ahead
//  - outputs staged in stage[wave][64 rows][128 slots] with diagonal slot
//    rotation phys = (c+4*row)&127 (write banks = (tau+3r) mod 32: 2-way
//    free; read: uniform 8 accesses/bank), flushed as 2x16-col blocks per
//    chunk: ds_read_b128 + coalesced 64B-per-row global_store_dwordx4
//  - barriers are LDS-only (no vmcnt drain): store stream never blocks

namespace {

constexpr int LLEN   = 1024;
constexpr int NCHAN  = 256;
constexpr int NTILE  = 16;                    // 64-row tiles per channel
constexpr int CHT    = 32;                    // ticks per chunk
constexpr int NQ     = 10;                    // chunks per tile (320 >= 319)
constexpr int NPHASE = 3 * (NTILE - 1) + NQ;  // 55
constexpr int SLOTS  = 128;                   // stage cols in flight (pow2)

constexpr int G_OFF   = 0;                    // g[1024]
constexpr int B_OFF   = LLEN;                 // beta[1024]
constexpr int BND_OFF = 2 * LLEN;             // bnd[16][256]
constexpr int STG_OFF = BND_OFF + NTILE * 256;// stage[4][64][SLOTS]
constexpr int LDS_FLOATS = STG_OFF + 4 * 64 * SLOTS;
constexpr size_t LDS_BYTES = (size_t)LDS_FLOATS * 4;  // 155648 B <= 160 KiB

using f32x4 = __attribute__((ext_vector_type(4))) float;

__device__ __forceinline__ float dpp_shr1(float v) {
    // lane i <- lane i-1; lane 0 <- old (=0)
    return __int_as_float(__builtin_amdgcn_update_dpp(
        0, __float_as_int(v), 0x138 /*WAVE_SHR1*/, 0xF, 0xF, false));
}

// LDS-only barrier: orders bnd handoffs without draining the store queue.
__device__ __forceinline__ void lds_barrier() {
    __builtin_amdgcn_sched_barrier(0);
    asm volatile("s_waitcnt lgkmcnt(0)" ::: "memory");
    __builtin_amdgcn_s_barrier();
    __builtin_amdgcn_sched_barrier(0);
}

// MODE: 0 = ramp (q 0-1: first-col inject + not-yet-started lanes),
//       1 = steady (q 2-7: no masking at all),
//       2 = drain (q 8-9: finished lanes freeze).
template <int MODE>
__device__ __forceinline__ void run_chunk(
    const int T0, const int lane, const int wave, const int k, const int ch,
    const float g, const float beta,
    float& x_cur, float& u_prev,
    float* __restrict__ lds, float* __restrict__ out)
{
    const bool lane0 = (lane == 0);
    float* __restrict__ stg = lds + STG_OFF + (wave << 13);        // 64*128
    const float* __restrict__ bnd_rd = lds + BND_OFF + (k << 8);
    float* __restrict__ bnd_wr = lds + BND_OFF + (((k + 1) & 15) << 8);
    const bool kw = (k < NTILE - 1) && (lane == 63);

    // boundary prefetch: 8 broadcast b128 reads (cols T0..T0+31 of bnd[k])
    float br[CHT];
    if (MODE < 2) {
        #pragma unroll
        for (int j = 0; j < CHT / 4; ++j) {
            const f32x4 t = *reinterpret_cast<const f32x4*>(bnd_rd + T0 + 4 * j);
            br[4*j+0] = t[0]; br[4*j+1] = t[1];
            br[4*j+2] = t[2]; br[4*j+3] = t[3];
        }
    }

    const int cb   = T0 - lane;                      // col at s=0
    const int pb   = (T0 + 3 * lane) & (SLOTS - 1);  // phys slot at s=0
    const int rowb = lane * SLOTS;

    #pragma unroll
    for (int s = 0; s < CHT; ++s) {
        const int c = cb + s;
        const float u_raw = dpp_shr1(x_cur);
        const float u = (MODE < 2 && lane0) ? br[s] : u_raw;
        float xn;
        if (MODE == 0) {
            const bool first = (c == 0);
            const float xp = first ? 0.0f : x_cur;
            const float uo = first ? 0.0f : u_prev;
            const float ba = first ? beta : 0.0f;
            xn = fmaf(g, xp + u, ba - uo);
        } else {
            xn = fmaf(g, x_cur + u, -u_prev);
        }
        // staging write, unconditional (garbage slots of out-of-range cols
        // alias cols +-128 whose valid write / flush ordering makes it safe)
        stg[rowb + ((pb + s) & (SLOTS - 1))] = xn;
        if (MODE == 0) {
            const bool act = (c >= 0);
            x_cur  = act ? xn : x_cur;
            u_prev = act ? u  : u_prev;
            if (kw && c == 0) bnd_wr[0] = xn;        // only q=1,s=31 fires
        } else if (MODE == 2) {
            const bool act = (c < 256);
            x_cur  = act ? xn : x_cur;
            u_prev = act ? u  : u_prev;
            if (kw && c < 256) bnd_wr[c] = xn;
        } else {
            x_cur  = xn;
            u_prev = u;
            if (kw) bnd_wr[c] = xn;                  // c in [1,224]: safe
        }
    }

    // flush 2 x 16-col blocks (C0 = T0-64, T0-48); block C0 fully written:
    // lane63 wrote col C0+15 at tick C0+78 <= T0+31 (margin 1 tick).
    if (MODE >= 1) {
        const int lam4 = (lane & 3) << 2;
        const int rr   = lane >> 2;
        #pragma unroll
        for (int blk = 0; blk < 2; ++blk) {
            const int C0 = T0 - 64 + 16 * blk;
            f32x4 v[4];
            #pragma unroll
            for (int j = 0; j < 4; ++j) {
                const int row  = rr + 16 * j;
                const int phys = (C0 + lam4 + 4 * row) & (SLOTS - 1);
                v[j] = *reinterpret_cast<const f32x4*>(&stg[row * SLOTS + phys]);
            }
            #pragma unroll
            for (int j = 0; j < 4; ++j) {
                const int row = rr + 16 * j;
                f32x4* p = reinterpret_cast<f32x4*>(
                    out + (size_t)(64 * k + row) * (NCHAN * 256)
                        + (ch << 8) + C0 + lam4);
                __builtin_nontemporal_store(v[j], p);
            }
        }
    }
}

__global__ __launch_bounds__(256, 1)
void toeplitz_scan(const float* __restrict__ vin,   // inputs (L, 256)
                   const float* __restrict__ dtin,  // dt     (L, 256)
                   float* __restrict__ out)         // (L, 256, 256)
{
    extern __shared__ float lds[];
    const int ch  = blockIdx.x;
    const int tid = threadIdx.x;

    // per-channel g[l], beta[l]
    #pragma unroll
    for (int k4 = 0; k4 < LLEN / 256; ++k4) {
        const int l = tid + 256 * k4;
        const float d = dtin[l * NCHAN + ch];
        const float u = vin[l * NCHAN + ch];
        const float ic = 1.0f / (1.0f + 0.25f * d);
        lds[G_OFF + l] = (1.0f - 0.25f * d) * ic;
        lds[B_OFF + l] = d * u * ic;
    }
    lds[BND_OFF + tid] = 0.0f;   // bnd[0] = zeros (row -1)
    __syncthreads();

    const int wave = tid >> 6, lane = tid & 63;
    float g = 0.0f, beta = 0.0f, x_cur = 0.0f, u_prev = 0.0f;

    for (int p = 0; p < NPHASE; ++p) {
        // tile k == wave (mod 4) with chunk q = p - 3k in [0, NQ): unique
        int k = -1, q = 0;
        const int kc = p / 3;
        #pragma unroll
        for (int j = 0; j < 4; ++j) {
            const int kk = kc - j;
            const int qq = p - 3 * kk;
            if (kk >= 0 && kk < NTILE && (kk & 3) == wave && qq < NQ) {
                k = kk; q = qq;
            }
        }
        if (k >= 0) {
            if (q == 0) {                 // new tile: per-lane row constants
                g    = lds[G_OFF + 64 * k + lane];
                beta = lds[B_OFF + 64 * k + lane];
            }
            const int T0 = CHT * q;
            if (q < 2)
                run_chunk<0>(T0, lane, wave, k, ch, g, beta, x_cur, u_prev, lds, out);
            else if (q < 8)
                run_chunk<1>(T0, lane, wave, k, ch, g, beta, x_cur, u_prev, lds, out);
            else
                run_chunk<2>(T0, lane, wave, k, ch, g, beta, x_cur, u_prev, lds, out);
        }
        lds_barrier();
    }
}

} // namespace

extern "C" void kernel_launch(void* const* d_in, const int* in_sizes, int n_in,
                              void* d_out, int out_size, void* d_ws, size_t ws_size,
                              hipStream_t stream) {
    (void)in_sizes; (void)n_in; (void)d_ws; (void)ws_size; (void)out_size;
    const float* vin  = (const float*)d_in[0];   // "inputs"
    const float* dtin = (const float*)d_in[1];   // "dt"
    float* out = (float*)d_out;

    (void)hipFuncSetAttribute(reinterpret_cast<const void*>(toeplitz_scan),
                              hipFuncAttributeMaxDynamicSharedMemorySize,
                              (int)LDS_BYTES);

    toeplitz_scan<<<NCHAN, 256, LDS_BYTES, stream>>>(vin, dtin, out);
}

// Round 9
// 65.627 us; speedup vs baseline: 1.7699x; 1.6871x over previous
//
#include <hip/hip_runtime.h>

// ToeplitzMemoryProjection (HiPPO LagT, alpha=0.5 bilinear).
//
// Recurrence (exact in the truncated lower-tri Toeplitz algebra, verified
// correct rounds 1-8): with c = 1+0.25dt, g = (1-0.25dt)/c, beta = dt*u/c,
//   x_l[i] = g_l*(x_l[i-1] + x_{l-1}[i]) - x_{l-1}[i-1] + beta_l*[i==0]
//
// R9 = R3's proven column-per-lane wavefront (KCH=32, SKEW=96, 4 waves,
// LDS-only barriers) with the DS-instruction count cut ~3x:
//  - ROW-indexed per-wave ring [128 slots][64 cols] (slot = row & 127).
//    Write: 1 ds_write_b32/tick, bank = lane%32 (2-way, free).
//    OOB-row garbage writes proven safe: negative rows alias slots whose
//    real row is written later (overwrites garbage); rows >= 1024 alias
//    slots already flushed (flush of row r-128 ends 2 ticks before the
//    garbage write can land).
//  - Flush in 4-row groups: lane j reads ring[F + (j>>4)][4*(j&15)..+3] as
//    ONE ds_read_b128 (banks even, 12-cy floor) + ONE dwordx4 nontemporal
//    store -> 8 b128 + 8 stores per chunk (was 32 b32 + 32 stores).
//    F = T0 - wskew - 64 is wave-uniform, multiple of 32; flush iff
//    0 <= F <= 992; covers every row exactly once; rows [F,F+31] complete
//    at tick T0+30 (own-wave program order, no barrier needed).
//  - Cross-wave handoff read directly from LEFT wave's row-ring col 63 at
//    slot = own row & 127 (left wrote row l at tick l+wskew-33 <= T0-2:
//    previous phase, barrier-ordered; left's concurrent writes cover slot
//    residues disjoint from [bl, bl+31] mod 128).
//  - g/b padded to 1152 (zeros) so wave-0 beta is 8 aligned b128 reads.

namespace {

constexpr int LLEN   = 1024;
constexpr int NCHAN  = 256;
constexpr int KCH    = 32;                 // ticks per chunk
constexpr int SKEW   = 96;                 // per-wave skew; 96-63=33 > KCH-1
constexpr int RSLOT  = 128;                // row slots per ring (pow2)
constexpr int NCHUNK = 43;                 // covers ticks [0,1376) >= 1375
constexpr int GPAD   = 1152;               // g/b padded length

constexpr int G_OFF = 0;
constexpr int B_OFF = GPAD;
constexpr int R_OFF = 2 * GPAD;
constexpr int LDS_FLOATS = R_OFF + 4 * RSLOT * 64;
constexpr size_t LDS_BYTES = (size_t)LDS_FLOATS * 4;   // 140288 B

using f32x4 = __attribute__((ext_vector_type(4))) float;

__device__ __forceinline__ float dpp_shr1(float v) {
    // lane i <- lane i-1; lane 0 <- old (=0)
    return __int_as_float(__builtin_amdgcn_update_dpp(
        0, __float_as_int(v), 0x138 /*WAVE_SHR1*/, 0xF, 0xF, false));
}

__device__ __forceinline__ void compiler_mem_fence() {
    asm volatile("" ::: "memory");
}

// LDS-only barrier: orders ring handoffs without draining the store queue.
__device__ __forceinline__ void lds_barrier() {
    __builtin_amdgcn_sched_barrier(0);
    asm volatile("s_waitcnt lgkmcnt(0)" ::: "memory");
    __builtin_amdgcn_s_barrier();
    __builtin_amdgcn_sched_barrier(0);
}

// One 32-tick chunk. hb source: W0 -> b_arr (beta, aligned b128);
// else -> left wave's ring col 63 at slot (row & 127).
template <bool W0, bool MASKED>
__device__ __forceinline__ void do_chunk(
    const int T0, const int bl, const int lane, const bool lane0,
    const float* __restrict__ g_arr, const float* __restrict__ hb_src,
    float* __restrict__ my_ring, float& prev_own, float& prev_left)
{
    float hb[KCH];
    if (W0) {
        #pragma unroll
        for (int q = 0; q < KCH / 4; ++q) {
            const f32x4 t =
                *reinterpret_cast<const f32x4*>(hb_src + T0 + 4 * q);
            hb[4*q+0] = t[0]; hb[4*q+1] = t[1];
            hb[4*q+2] = t[2]; hb[4*q+3] = t[3];
        }
    } else {
        #pragma unroll
        for (int s = 0; s < KCH; ++s)
            hb[s] = hb_src[(((bl + s) & (RSLOT - 1)) << 6) + 63];
    }

    const int m0 = bl - lane;              // this lane's row at s=0
    #pragma unroll
    for (int s = 0; s < KCH; ++s) {
        int li = m0 + s;
        if (MASKED) li = min(max(li, 0), LLEN - 1);
        const float gg = g_arr[li];
        float cl = dpp_shr1(prev_own);
        float ct;
        if (W0) {
            ct = (lane0 ? hb[s] : 0.0f) - prev_left;   // lane0: +beta
        } else {
            cl += lane0 ? hb[s] : 0.0f;                // lane0: handoff
            ct = 0.0f - prev_left;
        }
        const float x = fmaf(gg, cl, fmaf(gg, prev_own, ct));
        my_ring[(((m0 + s) & (RSLOT - 1)) << 6) + lane] = x;
        if (MASKED) {
            const bool act = (unsigned)(m0 + s) < (unsigned)LLEN;
            prev_left = act ? cl : prev_left;
            prev_own  = act ? x  : prev_own;
        } else {
            prev_left = cl;
            prev_own  = x;
        }
    }
}

__global__ __launch_bounds__(256, 1)
void toeplitz_scan(const float* __restrict__ vin,   // inputs (L, 256)
                   const float* __restrict__ dtin,  // dt     (L, 256)
                   float* __restrict__ out)         // (L, 256, 256)
{
    extern __shared__ float lds[];
    float* g_arr = lds + G_OFF;   // [GPAD]
    float* b_arr = lds + B_OFF;   // [GPAD]
    float* ring  = lds + R_OFF;   // [4][RSLOT][64], row-indexed slots

    const int ch  = blockIdx.x;
    const int tid = threadIdx.x;

    // ---- per-channel g[l], beta[l] (+ zero pad) ----
    #pragma unroll
    for (int k = 0; k < LLEN / 256; ++k) {
        const int l = tid + 256 * k;
        const float d = dtin[l * NCHAN + ch];
        const float u = vin[l * NCHAN + ch];
        const float ic = 1.0f / (1.0f + 0.25f * d);
        g_arr[l] = (1.0f - 0.25f * d) * ic;
        b_arr[l] = d * u * ic;
    }
    if (tid < GPAD - LLEN) {
        g_arr[LLEN + tid] = 1.0f;
        b_arr[LLEN + tid] = 0.0f;
    }
    __syncthreads();

    const int wave = tid >> 6, lane = tid & 63;
    const bool w0    = (wave == 0);
    const bool lane0 = (lane == 0);
    const int wskew  = wave * SKEW;

    float* my_ring = ring + wave * (RSLOT * 64);
    const float* lf_ring = ring + (wave - 1) * (RSLOT * 64);  // wave>0 only

    float prev_own = 0.0f, prev_left = 0.0f;

    const int rq = lane >> 4;              // flush: row within 4-row group
    const int cq = (lane & 15) << 2;       // flush: col-quad start
    float* const out_col = out + (size_t)(ch * 256 + wave * 64 + cq);

    for (int c = 0; c < NCHUNK; ++c) {
        const int T0 = c * KCH;
        const int bl = T0 - wskew;         // lane0's row at s=0 (mult of 32)

        if (bl >= 0 && bl <= 1056) {       // any lane active this chunk
            const bool fast = (bl >= 64) && (bl <= LLEN - KCH);
            if (w0) {
                if (fast)
                    do_chunk<true, false>(T0, bl, lane, lane0, g_arr, b_arr,
                                          my_ring, prev_own, prev_left);
                else
                    do_chunk<true, true>(T0, bl, lane, lane0, g_arr, b_arr,
                                         my_ring, prev_own, prev_left);
            } else {
                if (fast)
                    do_chunk<false, false>(T0, bl, lane, lane0, g_arr, lf_ring,
                                           my_ring, prev_own, prev_left);
                else
                    do_chunk<false, true>(T0, bl, lane, lane0, g_arr, lf_ring,
                                          my_ring, prev_own, prev_left);
            }
        }

        // ---- flush rows [F, F+31] (4-row groups; complete at tick T0+30) --
        const int F = T0 - wskew - 64;
        if (F >= 0 && F <= LLEN - KCH) {
            compiler_mem_fence();          // ring writes stay above reads
            const float* rb = my_ring + ((F & (RSLOT - 1)) << 6) + cq;
            float* ob = out_col + (size_t)(F + rq) * (NCHAN * 256);
            #pragma unroll
            for (int q = 0; q < 8; ++q) {
                const f32x4 v =
                    *reinterpret_cast<const f32x4*>(rb + ((4 * q + rq) << 6));
                __builtin_nontemporal_store(v, reinterpret_cast<f32x4*>(ob));
                ob += (size_t)4 * (NCHAN * 256);
            }
        }
        lds_barrier();
    }
}

} // namespace

extern "C" void kernel_launch(void* const* d_in, const int* in_sizes, int n_in,
                              void* d_out, int out_size, void* d_ws, size_t ws_size,
                              hipStream_t stream) {
    (void)in_sizes; (void)n_in; (void)d_ws; (void)ws_size; (void)out_size;
    const float* vin  = (const float*)d_in[0];   // "inputs"
    const float* dtin = (const float*)d_in[1];   // "dt"
    float* out = (float*)d_out;

    (void)hipFuncSetAttribute(reinterpret_cast<const void*>(toeplitz_scan),
                              hipFuncAttributeMaxDynamicSharedMemorySize,
                              (int)LDS_BYTES);

    toeplitz_scan<<<NCHAN, 256, LDS_BYTES, stream>>>(vin, dtin, out);
}